// Round 1
// baseline (871.787 us; speedup 1.0000x reference)
//
#include <hip/hip_runtime.h>
#include <math.h>

#define B_  2
#define S_  2048
#define D_  1024
#define H_  16
#define DH_ 64
#define BH_ (B_ * H_)

// Static device scratch for q/k/v in [B,H,S,dh] layout (no ws_size assumptions).
__device__ float g_q[(size_t)BH_ * S_ * DH_];
__device__ float g_k[(size_t)BH_ * S_ * DH_];
__device__ float g_v[(size_t)BH_ * S_ * DH_];

// ---------------------------------------------------------------------------
// Kernel 1: QKV projection.  C[M=4096][N=3072] = X[4096][1024] @ W^T + bias
// 64x64 tile per block, 256 threads, 4x4 per thread, K-tile 32.
// Both A (X) and B (W) are K-contiguous, staged transposed in LDS so the
// inner loop does two float4 LDS reads + 16 FMA per k.
// Output scattered into g_q/g_k/g_v ([B,H,S,dh]); q pre-scaled by 32 (exact).
// ---------------------------------------------------------------------------
__global__ __launch_bounds__(256) void qkv_proj_f32(
    const float* __restrict__ X,
    const float* __restrict__ W,
    const float* __restrict__ bias)
{
    __shared__ float At[32][68];  // [k][row], pad 68 => float4-aligned, no read conflicts
    __shared__ float Bt[32][68];  // [k][col]

    const int tid = threadIdx.x;
    const int ty = tid >> 4;      // 0..15 -> row group
    const int tx = tid & 15;      // 0..15 -> col group
    const int row0 = blockIdx.x * 64;
    const int col0 = blockIdx.y * 64;

    float acc[4][4] = {};

    for (int k0 = 0; k0 < D_; k0 += 32) {
#pragma unroll
        for (int rep = 0; rep < 8; ++rep) {
            int idx = rep * 256 + tid;     // 0..2047
            int r  = idx >> 5;             // 0..63 tile row
            int kk = idx & 31;             // 0..31 k
            At[kk][r] = X[(size_t)(row0 + r) * D_ + k0 + kk];
            Bt[kk][r] = W[(size_t)(col0 + r) * D_ + k0 + kk];
        }
        __syncthreads();
#pragma unroll 8
        for (int kk = 0; kk < 32; ++kk) {
            float4 a = *(const float4*)&At[kk][ty * 4];
            float4 b = *(const float4*)&Bt[kk][tx * 4];
            float av[4] = {a.x, a.y, a.z, a.w};
            float bv[4] = {b.x, b.y, b.z, b.w};
#pragma unroll
            for (int j = 0; j < 4; ++j)
#pragma unroll
                for (int i = 0; i < 4; ++i)
                    acc[j][i] += av[j] * bv[i];
        }
        __syncthreads();
    }

    // Epilogue: bias add, scatter to q/k/v [B,H,S,dh].
    // col tile (64 wide, 64-aligned) lies within one (which, h).
    const int which = col0 >> 10;           // 0=q 1=k 2=v
    const int h     = (col0 & 1023) >> 6;   // head
    float* dst = (which == 0) ? g_q : (which == 1) ? g_k : g_v;
    const float sc = (which == 0) ? 32.0f : 1.0f;  // fold logit scale into q (exact pow2)

    float4 bb;
    bb.x = bias[col0 + tx * 4 + 0];
    bb.y = bias[col0 + tx * 4 + 1];
    bb.z = bias[col0 + tx * 4 + 2];
    bb.w = bias[col0 + tx * 4 + 3];

#pragma unroll
    for (int j = 0; j < 4; ++j) {
        int r = row0 + ty * 4 + j;          // global row in [0, B*S)
        int b = r >> 11;                    // /2048
        int s = r & 2047;
        float4 o;
        o.x = (acc[j][0] + bb.x) * sc;
        o.y = (acc[j][1] + bb.y) * sc;
        o.z = (acc[j][2] + bb.z) * sc;
        o.w = (acc[j][3] + bb.w) * sc;
        *(float4*)&dst[(((size_t)(b * H_ + h)) * S_ + s) * DH_ + tx * 4] = o;
    }
}

// ---------------------------------------------------------------------------
// Kernel 2: flash-style attention, fp32.
// Block = (b, h, 64-row q-tile), 256 threads, 4x4 register tiles.
// Online softmax per row; row reductions via __shfl_xor over the 16-lane
// tx group (lane bits 0..3). P staged through LDS for the PV product.
// ---------------------------------------------------------------------------
__global__ __launch_bounds__(256) void attn_f32(float* __restrict__ out)
{
    __shared__ float Qt[64][68];  // [d][row]   (Q pre-scaled by 32)
    __shared__ float Kt[64][68];  // [d][key]
    __shared__ float Vs[64][68];  // [key][d]
    __shared__ float Ps[64][68];  // [row][key]

    const int tid = threadIdx.x;
    const int ty = tid >> 4;      // row group 0..15
    const int tx = tid & 15;      // col group 0..15
    const int bh = blockIdx.y;    // b*16 + h
    const int q0 = blockIdx.x * 64;

    const size_t base = (size_t)bh * S_ * DH_;
    const float* Q = g_q + base;
    const float* K = g_k + base;
    const float* V = g_v + base;

#pragma unroll
    for (int rep = 0; rep < 16; ++rep) {
        int idx = rep * 256 + tid;
        int r = idx >> 6, d = idx & 63;
        Qt[d][r] = Q[(size_t)(q0 + r) * DH_ + d];
    }

    float m[4], l[4], o[4][4];
#pragma unroll
    for (int j = 0; j < 4; ++j) {
        m[j] = -1e30f;
        l[j] = 0.0f;
#pragma unroll
        for (int i = 0; i < 4; ++i) o[j][i] = 0.0f;
    }
    __syncthreads();

    for (int t0 = 0; t0 < S_; t0 += 64) {
#pragma unroll
        for (int rep = 0; rep < 16; ++rep) {
            int idx = rep * 256 + tid;
            int r = idx >> 6, d = idx & 63;
            Kt[d][r] = K[(size_t)(t0 + r) * DH_ + d];
            Vs[r][d] = V[(size_t)(t0 + r) * DH_ + d];
        }
        __syncthreads();

        // S-tile = Q_tile @ K_tile^T (already scaled by 32 via Q)
        float s[4][4] = {};
#pragma unroll 8
        for (int d = 0; d < 64; ++d) {
            float4 a = *(const float4*)&Qt[d][ty * 4];
            float4 b = *(const float4*)&Kt[d][tx * 4];
            float av[4] = {a.x, a.y, a.z, a.w};
            float bv[4] = {b.x, b.y, b.z, b.w};
#pragma unroll
            for (int j = 0; j < 4; ++j)
#pragma unroll
                for (int i = 0; i < 4; ++i)
                    s[j][i] += av[j] * bv[i];
        }

        // Online softmax (per row j; rows live in the 16-lane tx group)
#pragma unroll
        for (int j = 0; j < 4; ++j) {
            float mt = fmaxf(fmaxf(s[j][0], s[j][1]), fmaxf(s[j][2], s[j][3]));
            mt = fmaxf(mt, __shfl_xor(mt, 1));
            mt = fmaxf(mt, __shfl_xor(mt, 2));
            mt = fmaxf(mt, __shfl_xor(mt, 4));
            mt = fmaxf(mt, __shfl_xor(mt, 8));
            float mn = fmaxf(m[j], mt);
            float corr = __expf(m[j] - mn);
            float sum = 0.0f;
#pragma unroll
            for (int i = 0; i < 4; ++i) {
                s[j][i] = __expf(s[j][i] - mn);
                sum += s[j][i];
            }
            sum += __shfl_xor(sum, 1);
            sum += __shfl_xor(sum, 2);
            sum += __shfl_xor(sum, 4);
            sum += __shfl_xor(sum, 8);
            l[j] = l[j] * corr + sum;
            m[j] = mn;
#pragma unroll
            for (int i = 0; i < 4; ++i) o[j][i] *= corr;
            float4 p4 = make_float4(s[j][0], s[j][1], s[j][2], s[j][3]);
            *(float4*)&Ps[ty * 4 + j][tx * 4] = p4;
        }
        __syncthreads();

        // O += P @ V
#pragma unroll 8
        for (int kk = 0; kk < 64; ++kk) {
            float4 vv = *(const float4*)&Vs[kk][tx * 4];
            float vvv[4] = {vv.x, vv.y, vv.z, vv.w};
            float p0 = Ps[ty * 4 + 0][kk];
            float p1 = Ps[ty * 4 + 1][kk];
            float p2 = Ps[ty * 4 + 2][kk];
            float p3 = Ps[ty * 4 + 3][kk];
#pragma unroll
            for (int i = 0; i < 4; ++i) {
                o[0][i] += p0 * vvv[i];
                o[1][i] += p1 * vvv[i];
                o[2][i] += p2 * vvv[i];
                o[3][i] += p3 * vvv[i];
            }
        }
        __syncthreads();
    }

    // Epilogue: out[b][q0+r][h*64 + c] = o / l
    const int b = bh >> 4;
    const int h = bh & 15;
#pragma unroll
    for (int j = 0; j < 4; ++j) {
        float inv = 1.0f / l[j];
        int r = q0 + ty * 4 + j;
        float4 o4 = make_float4(o[j][0] * inv, o[j][1] * inv,
                                o[j][2] * inv, o[j][3] * inv);
        *(float4*)&out[((size_t)(b * S_ + r)) * D_ + h * DH_ + tx * 4] = o4;
    }
}

extern "C" void kernel_launch(void* const* d_in, const int* in_sizes, int n_in,
                              void* d_out, int out_size, void* d_ws, size_t ws_size,
                              hipStream_t stream) {
    const float* X    = (const float*)d_in[0];  // query [B,S,D]
    // d_in[1] (key), d_in[2] (value) are ignored by the reference module.
    const float* W    = (const float*)d_in[3];  // [3D, D]
    const float* bias = (const float*)d_in[4];  // [3D]
    float* out = (float*)d_out;

    dim3 gProj(64, 48);   // M/64 x N/64  (M=4096, N=3072)
    qkv_proj_f32<<<gProj, 256, 0, stream>>>(X, W, bias);

    dim3 gAttn(S_ / 64, BH_);  // 32 q-tiles x 32 (b,h)
    attn_f32<<<gAttn, 256, 0, stream>>>(out);
}

// Round 2
// 305.955 us; speedup vs baseline: 2.8494x; 2.8494x over previous
//
#include <hip/hip_runtime.h>

#define B_  2
#define S_  2048
#define D_  1024
#define H_  16
#define DH_ 64
#define BH_ (B_*H_)

using f32x4   = __attribute__((ext_vector_type(4))) float;
using short4v = __attribute__((ext_vector_type(4))) short;
using short8v = __attribute__((ext_vector_type(8))) short;

// Scratch: q (pre-scaled x32) / k in [bh][s][dh]; v TRANSPOSED in [bh][dh][s]
__device__ float g_q [(size_t)BH_*S_*DH_];
__device__ float g_k [(size_t)BH_*S_*DH_];
__device__ float g_vt[(size_t)BH_*DH_*S_];

__device__ __forceinline__ short f2bf(float x){
  unsigned u = __builtin_bit_cast(unsigned, x);
  u += 0x7fffu + ((u >> 16) & 1u);           // RNE
  return (short)(unsigned short)(u >> 16);
}
__device__ __forceinline__ float bf2f(short h){
  return __builtin_bit_cast(float, ((unsigned)(unsigned short)h) << 16);
}
__device__ __forceinline__ void split4f(const float4 v, short4v& h4, short4v& l4){
  float f[4] = {v.x, v.y, v.z, v.w};
#pragma unroll
  for (int i = 0; i < 4; ++i){
    short hh = f2bf(f[i]);
    h4[i] = hh;
    l4[i] = f2bf(f[i] - bf2f(hh));
  }
}

#define MFMA16(A,B,C) __builtin_amdgcn_mfma_f32_16x16x32_bf16((A),(B),(C),0,0,0)

// ---------------------------------------------------------------------------
// QKV projection, split-bf16 MFMA.  C[4096][3072] = X @ W^T + bias.
// 128x128 tile, 4 waves (2x2), BK=32. A,B staged as bf16 hi/lo in LDS.
// q scaled x32 (exact pow2); v written transposed to g_vt.
// ---------------------------------------------------------------------------
__global__ __launch_bounds__(256) void qkv_proj_mfma(
    const float* __restrict__ X, const float* __restrict__ W,
    const float* __restrict__ bias)
{
  __shared__ short AH[128][40], AL[128][40], BHs[128][40], BLs[128][40];

  const int tid = threadIdx.x;
  const int w  = tid >> 6;
  const int ln = tid & 15;          // lane&15
  const int g  = (tid & 63) >> 4;   // lane>>4
  const int wr = w >> 1, wc = w & 1;
  const int m0 = blockIdx.y * 128;
  const int n0 = blockIdx.x * 128;

  f32x4 zero4 = {0.f, 0.f, 0.f, 0.f};
  f32x4 acc[4][4];
#pragma unroll
  for (int mf = 0; mf < 4; ++mf)
#pragma unroll
    for (int nf = 0; nf < 4; ++nf) acc[mf][nf] = zero4;

  for (int k0 = 0; k0 < D_; k0 += 32) {
#pragma unroll
    for (int rep = 0; rep < 4; ++rep) {
      int idx = rep * 256 + tid;         // 0..1023
      int r  = idx >> 3;                 // 0..127
      int c4 = (idx & 7) << 2;           // 0..28
      float4 a = *(const float4*)&X[(size_t)(m0 + r) * D_ + k0 + c4];
      float4 b = *(const float4*)&W[(size_t)(n0 + r) * D_ + k0 + c4];
      short4v ah4, al4, bh4, bl4;
      split4f(a, ah4, al4);
      split4f(b, bh4, bl4);
      *(short4v*)&AH [r][c4] = ah4;
      *(short4v*)&AL [r][c4] = al4;
      *(short4v*)&BHs[r][c4] = bh4;
      *(short4v*)&BLs[r][c4] = bl4;
    }
    __syncthreads();

    short8v ah[4], al[4], bhf[4], blf[4];
#pragma unroll
    for (int mf = 0; mf < 4; ++mf) {
      ah[mf] = *(const short8v*)&AH[64*wr + 16*mf + ln][8*g];
      al[mf] = *(const short8v*)&AL[64*wr + 16*mf + ln][8*g];
    }
#pragma unroll
    for (int nf = 0; nf < 4; ++nf) {
      bhf[nf] = *(const short8v*)&BHs[64*wc + 16*nf + ln][8*g];
      blf[nf] = *(const short8v*)&BLs[64*wc + 16*nf + ln][8*g];
    }
#pragma unroll
    for (int mf = 0; mf < 4; ++mf)
#pragma unroll
      for (int nf = 0; nf < 4; ++nf) {
        acc[mf][nf] = MFMA16(ah[mf], bhf[nf], acc[mf][nf]);
        acc[mf][nf] = MFMA16(al[mf], bhf[nf], acc[mf][nf]);
        acc[mf][nf] = MFMA16(ah[mf], blf[nf], acc[mf][nf]);
      }
    __syncthreads();
  }

  // Epilogue. D layout: row=(lane>>4)*4+reg, col=lane&15 (HW-verified).
  const int which = n0 >> 10;   // 0=q 1=k 2=v (tile never straddles: 1024%128==0)
#pragma unroll
  for (int nf = 0; nf < 4; ++nf) {
    int col = n0 + 64*wc + 16*nf + ln;
    float bb = bias[col];
    int hh = (col & 1023) >> 6;
    int dh = col & 63;
#pragma unroll
    for (int mf = 0; mf < 4; ++mf) {
      int row0 = m0 + 64*wr + 16*mf + 4*g;   // 4 consecutive rows (regs)
      int bidx = row0 >> 11;
      int s0   = row0 & 2047;
      if (which == 2) {
        f32x4 v;
#pragma unroll
        for (int i = 0; i < 4; ++i) v[i] = acc[mf][nf][i] + bb;
        *(f32x4*)&g_vt[(((size_t)bidx * H_ + hh) * DH_ + dh) * S_ + s0] = v;
      } else {
        float* dst = (which == 0) ? g_q : g_k;
        float sc   = (which == 0) ? 32.0f : 1.0f;
#pragma unroll
        for (int i = 0; i < 4; ++i)
          dst[(((size_t)bidx * H_ + hh) * S_ + s0 + i) * DH_ + dh] =
              (acc[mf][nf][i] + bb) * sc;
      }
    }
  }
}

// ---------------------------------------------------------------------------
// Flash attention, MFMA. Block = (64 q-rows, bh); 4 waves x 16 rows.
// QK^T split-bf16 (Q regs hi/lo, K LDS hi/lo), online softmax on D-frags,
// P->LDS bf16 (per-wave), PV plain bf16 (V staged [dh][key] from g_vt).
// ---------------------------------------------------------------------------
__global__ __launch_bounds__(256) void attn_mfma(float* __restrict__ out)
{
  __shared__ short KH[64][72], KL[64][72], VT[64][72];
  __shared__ short PS[4][16][72];

  const int tid = threadIdx.x;
  const int w  = tid >> 6;
  const int ln = tid & 15;
  const int g  = (tid & 63) >> 4;
  const int bh = blockIdx.y;
  const int q0 = blockIdx.x * 64;
  const int b  = bh >> 4, h = bh & 15;

  const float* Qp = g_q  + (size_t)bh * S_ * DH_;
  const float* Kp = g_k  + (size_t)bh * S_ * DH_;
  const float* Vp = g_vt + (size_t)bh * DH_ * S_;

  // Q fragments (A: row=lane&15, k=8*(lane>>4)+j per 32-wide k-step), hi/lo.
  short8v qh[2], ql[2];
  {
    const float* qr = &Qp[(size_t)(q0 + 16*w + ln) * DH_];
#pragma unroll
    for (int ks = 0; ks < 2; ++ks) {
      int d0 = 32*ks + 8*g;
      float4 f0 = *(const float4*)&qr[d0];
      float4 f1 = *(const float4*)&qr[d0 + 4];
      float f[8] = {f0.x,f0.y,f0.z,f0.w,f1.x,f1.y,f1.z,f1.w};
#pragma unroll
      for (int j = 0; j < 8; ++j) {
        short hh = f2bf(f[j]);
        qh[ks][j] = hh;
        ql[ks][j] = f2bf(f[j] - bf2f(hh));
      }
    }
  }

  f32x4 zero4 = {0.f,0.f,0.f,0.f};
  f32x4 o[4];
  float m_[4], l_[4];
#pragma unroll
  for (int i = 0; i < 4; ++i) { o[i] = zero4; m_[i] = -1e30f; l_[i] = 0.f; }

  for (int t0 = 0; t0 < S_; t0 += 64) {
    // stage K (hi/lo) as [key][dh], V as [dh][key] (linear: g_vt transposed)
#pragma unroll
    for (int rep = 0; rep < 4; ++rep) {
      int idx = rep * 256 + tid;
      int r  = idx >> 4;               // 0..63
      int c4 = (idx & 15) << 2;        // 0..60
      float4 kv = *(const float4*)&Kp[(size_t)(t0 + r) * DH_ + c4];
      short4v h4, l4;
      split4f(kv, h4, l4);
      *(short4v*)&KH[r][c4] = h4;
      *(short4v*)&KL[r][c4] = l4;
      float4 vv = *(const float4*)&Vp[(size_t)r * S_ + t0 + c4];
      short4v v4;
      v4[0] = f2bf(vv.x); v4[1] = f2bf(vv.y); v4[2] = f2bf(vv.z); v4[3] = f2bf(vv.w);
      *(short4v*)&VT[r][c4] = v4;
    }
    __syncthreads();

    // S = Q K^T  (x32 already folded into Q)
    f32x4 s[4];
#pragma unroll
    for (int nf = 0; nf < 4; ++nf) s[nf] = zero4;
#pragma unroll
    for (int ks = 0; ks < 2; ++ks) {
#pragma unroll
      for (int nf = 0; nf < 4; ++nf) {
        const short8v kh = *(const short8v*)&KH[16*nf + ln][32*ks + 8*g];
        const short8v kl = *(const short8v*)&KL[16*nf + ln][32*ks + 8*g];
        s[nf] = MFMA16(qh[ks], kh, s[nf]);
        s[nf] = MFMA16(ql[ks], kh, s[nf]);
        s[nf] = MFMA16(qh[ks], kl, s[nf]);
      }
    }

    // online softmax; rows = 4*g + i, cols = 16*nf + ln
#pragma unroll
    for (int i = 0; i < 4; ++i) {
      float mt = fmaxf(fmaxf(s[0][i], s[1][i]), fmaxf(s[2][i], s[3][i]));
      mt = fmaxf(mt, __shfl_xor(mt, 1));
      mt = fmaxf(mt, __shfl_xor(mt, 2));
      mt = fmaxf(mt, __shfl_xor(mt, 4));
      mt = fmaxf(mt, __shfl_xor(mt, 8));
      float mn = fmaxf(m_[i], mt);
      float corr = __expf(m_[i] - mn);
      float sum = 0.f;
#pragma unroll
      for (int nf = 0; nf < 4; ++nf) {
        float p = __expf(s[nf][i] - mn);
        sum += p;
        s[nf][i] = p;
      }
      sum += __shfl_xor(sum, 1);
      sum += __shfl_xor(sum, 2);
      sum += __shfl_xor(sum, 4);
      sum += __shfl_xor(sum, 8);
      l_[i] = l_[i] * corr + sum;
      m_[i] = mn;
#pragma unroll
      for (int nf = 0; nf < 4; ++nf) {
        o[nf][i] *= corr;
        PS[w][4*g + i][16*nf + ln] = f2bf(s[nf][i]);
      }
    }

    // O += P V   (A=P rows=lane&15; B=V cols(dh)=lane&15; k=key consistent)
#pragma unroll
    for (int ks = 0; ks < 2; ++ks) {
      const short8v pa = *(const short8v*)&PS[w][ln][32*ks + 8*g];
#pragma unroll
      for (int nf = 0; nf < 4; ++nf) {
        const short8v vb = *(const short8v*)&VT[16*nf + ln][32*ks + 8*g];
        o[nf] = MFMA16(pa, vb, o[nf]);
      }
    }
    __syncthreads();
  }

  // epilogue: out[b][row][h*64 + 16*nf + ln]
#pragma unroll
  for (int i = 0; i < 4; ++i) {
    float inv = 1.0f / l_[i];
    int row = q0 + 16*w + 4*g + i;
    float* op = &out[((size_t)b * S_ + row) * D_ + h * DH_];
#pragma unroll
    for (int nf = 0; nf < 4; ++nf)
      op[16*nf + ln] = o[nf][i] * inv;
  }
}

extern "C" void kernel_launch(void* const* d_in, const int* in_sizes, int n_in,
                              void* d_out, int out_size, void* d_ws, size_t ws_size,
                              hipStream_t stream) {
    (void)d_ws; (void)ws_size; (void)n_in; (void)in_sizes;
    const float* X    = (const float*)d_in[0];  // query [B,S,D]
    const float* W    = (const float*)d_in[3];  // [3D, D]
    const float* bias = (const float*)d_in[4];  // [3D]
    float* out = (float*)d_out;

    dim3 gProj(24, 32);        // N/128 x M/128
    qkv_proj_mfma<<<gProj, 256, 0, stream>>>(X, W, bias);

    dim3 gAttn(S_ / 64, BH_);  // 32 q-tiles x 32 (b,h)
    attn_mfma<<<gAttn, 256, 0, stream>>>(out);
}